// Round 6
// baseline (674.368 us; speedup 1.0000x reference)
//
#include <hip/hip_runtime.h>
#include <hip/hip_cooperative_groups.h>

namespace cg = cooperative_groups;

#define GN   4096
#define KS   4                 // split-K slabs for A@h
#define NBLK 256               // 1 block/CU -- cooperative launch always valid
#define NTHR (NBLK * 256)
#define NWAVE (NBLK * 4)

typedef __attribute__((ext_vector_type(8))) short bf16x8_t;
typedef __attribute__((ext_vector_type(4))) float f32x4_t;

__device__ __forceinline__ unsigned rne(unsigned u) {
    return u + 0x7fffu + ((u >> 16) & 1u);
}
__device__ __forceinline__ unsigned pkbf(float x, float y) {
    union { float f; unsigned u; } a, b; a.f = x; b.f = y;
    return (rne(a.u) >> 16) | (rne(b.u) & 0xffff0000u);   // low short = bf16(x)
}
__device__ __forceinline__ bf16x8_t cvt8(float4 a0, float4 a1) {
    union { unsigned u[4]; bf16x8_t v; } r;
    r.u[0] = pkbf(a0.x, a0.y);
    r.u[1] = pkbf(a0.z, a0.w);
    r.u[2] = pkbf(a1.x, a1.y);
    r.u[3] = pkbf(a1.z, a1.w);
    return r.v;
}
__device__ __forceinline__ short f2bf(float x) {
    union { float f; unsigned u; } c; c.f = x;
    return (short)(rne(c.u) >> 16);
}
__device__ __forceinline__ float bf2f(short s) {
    union { unsigned u; float f; } c; c.u = ((unsigned)(unsigned short)s) << 16;
    return c.f;
}
// split 8 fp32 into hi (bf16 RNE) + lo (bf16 of residual): ~16-bit mantissa
__device__ __forceinline__ void split8(float4 a0, float4 a1, bf16x8_t& hi, bf16x8_t& lo) {
    float v[8] = {a0.x, a0.y, a0.z, a0.w, a1.x, a1.y, a1.z, a1.w};
    union { short s[8]; bf16x8_t t; } H, L;
    #pragma unroll
    for (int i = 0; i < 8; ++i) {
        short h = f2bf(v[i]);
        H.s[i] = h;
        L.s[i] = f2bf(v[i] - bf2f(h));
    }
    hi = H.t; lo = L.t;
}
__device__ __forceinline__ void split8p(const float* p, bf16x8_t& hi, bf16x8_t& lo) {
    split8(*(const float4*)p, *(const float4*)(p + 4), hi, lo);
}

__global__ __launch_bounds__(256) void fused_k(
    const float* __restrict__ X, const float* __restrict__ A,
    const float* __restrict__ Wenc, const float* __restrict__ benc,
    const float* __restrict__ W1, const float* __restrict__ b1,
    const float* __restrict__ W2, const float* __restrict__ b2,
    const float* __restrict__ W3, const float* __restrict__ b3,
    const float* __restrict__ Wedge,
    float* __restrict__ part, short* __restrict__ Abf,
    float* __restrict__ h, short* __restrict__ Ht,
    float* __restrict__ s_i, float* __restrict__ s_j)
{
    cg::grid_group grid = cg::this_grid();
    const int tid  = blockIdx.x * 256 + threadIdx.x;
    const int wid  = blockIdx.x * 4 + (threadIdx.x >> 6);
    const int lane = threadIdx.x & 63;
    const int quad = lane >> 4, l16 = lane & 15;

    // ---- phase 0a: encoder h = relu(X @ Wenc^T + benc), h fp32 + Ht bf16
    for (int g = tid; g < GN * 64; g += NTHR) {
        const int i = g >> 6, f = g & 63;
        const float4 x0 = *(const float4*)(X + i * 8);
        const float4 x1 = *(const float4*)(X + i * 8 + 4);
        const float4 w0 = *(const float4*)(Wenc + f * 8);
        const float4 w1 = *(const float4*)(Wenc + f * 8 + 4);
        float acc = benc[f]
                  + x0.x * w0.x + x0.y * w0.y + x0.z * w0.z + x0.w * w0.w
                  + x1.x * w1.x + x1.y * w1.y + x1.z * w1.z + x1.w * w1.w;
        acc = fmaxf(acc, 0.f);
        h[g] = acc;
        Ht[f * GN + i] = f2bf(acc);
    }
    // ---- phase 0b: A fp32 -> bf16 once (halves per-round A traffic)
    #pragma unroll 4
    for (int g = tid; g < GN * GN / 8; g += NTHR) {
        const size_t base = (size_t)g * 8;
        float4 a0 = *(const float4*)(A + base);
        float4 a1 = *(const float4*)(A + base + 4);
        *(bf16x8_t*)(Abf + base) = cvt8(a0, a1);
    }
    __threadfence();
    grid.sync();

    for (int r = 0; r < 3; ++r) {
        const float* Wr = (r == 0) ? W1 : (r == 1) ? W2 : W3;
        const float* br = (r == 0) ? b1 : (r == 1) ? b2 : b3;

        // ---- gemm: part[ks] = Abf[16-row tile][kseg] @ Ht^T, barrier-free
        {
            const int ks = wid >> 8;               // 0..3
            const int m0 = (wid & 255) << 4;       // 16-row subtile
            const int kb = ks * (GN / KS);

            const short* aP = Abf + (size_t)(m0 + l16) * GN + kb + quad * 8;
            const short* bP = Ht  + (size_t)l16 * GN + kb + quad * 8;

            f32x4_t acc0 = {0.f, 0.f, 0.f, 0.f};
            f32x4_t acc1 = acc0, acc2 = acc0, acc3 = acc0;

            #pragma unroll 4
            for (int kk = 0; kk < GN / KS; kk += 32) {
                bf16x8_t af  = *(const bf16x8_t*)(aP + kk);
                bf16x8_t b0v = *(const bf16x8_t*)(bP + kk);
                bf16x8_t b1v = *(const bf16x8_t*)(bP + kk + 16 * GN);
                bf16x8_t b2v = *(const bf16x8_t*)(bP + kk + 32 * GN);
                bf16x8_t b3v = *(const bf16x8_t*)(bP + kk + 48 * GN);
                acc0 = __builtin_amdgcn_mfma_f32_16x16x32_bf16(af, b0v, acc0, 0, 0, 0);
                acc1 = __builtin_amdgcn_mfma_f32_16x16x32_bf16(af, b1v, acc1, 0, 0, 0);
                acc2 = __builtin_amdgcn_mfma_f32_16x16x32_bf16(af, b2v, acc2, 0, 0, 0);
                acc3 = __builtin_amdgcn_mfma_f32_16x16x32_bf16(af, b3v, acc3, 0, 0, 0);
            }
            float* o = part + ((size_t)ks * GN + m0 + quad * 4) * 64 + l16;
            #pragma unroll
            for (int rr = 0; rr < 4; ++rr) {
                o[rr * 64 +  0] = acc0[rr];
                o[rr * 64 + 16] = acc1[rr];
                o[rr * 64 + 32] = acc2[rr];
                o[rr * 64 + 48] = acc3[rr];
            }
        }
        __threadfence();
        grid.sync();

        // ---- dense: h = relu([h, sum part] @ W^T + b), split-bf16 MFMA ---
        // one W-fragment pair live at a time (register pressure control)
        if (wid < 256) {
            const int m0 = wid << 4;
            f32x4_t acc[4];
            #pragma unroll
            for (int n = 0; n < 4; ++n) acc[n] = (f32x4_t){0.f, 0.f, 0.f, 0.f};

            #pragma unroll
            for (int half = 0; half < 2; ++half) {
                #pragma unroll
                for (int kk = 0; kk < 64; kk += 32) {
                    const int kq = kk + quad * 8;
                    bf16x8_t ah, al;
                    if (half == 0) {
                        split8p(h + (size_t)(m0 + l16) * 64 + kq, ah, al);
                    } else {
                        const size_t base = (size_t)(m0 + l16) * 64 + kq;
                        float4 s0 = make_float4(0.f, 0.f, 0.f, 0.f);
                        float4 s1 = make_float4(0.f, 0.f, 0.f, 0.f);
                        #pragma unroll
                        for (int p = 0; p < KS; ++p) {
                            const float* pp = part + (size_t)p * (GN * 64) + base;
                            float4 v0 = *(const float4*)pp;
                            float4 v1 = *(const float4*)(pp + 4);
                            s0.x += v0.x; s0.y += v0.y; s0.z += v0.z; s0.w += v0.w;
                            s1.x += v1.x; s1.y += v1.y; s1.z += v1.z; s1.w += v1.w;
                        }
                        split8(s0, s1, ah, al);
                    }
                    const float* wp = Wr + half * 64 + kq;
                    #pragma unroll
                    for (int n = 0; n < 4; ++n) {
                        bf16x8_t bh, bl;
                        split8p(wp + (size_t)(l16 + 16 * n) * 128, bh, bl);
                        acc[n] = __builtin_amdgcn_mfma_f32_16x16x32_bf16(ah, bh, acc[n], 0, 0, 0);
                        acc[n] = __builtin_amdgcn_mfma_f32_16x16x32_bf16(ah, bl, acc[n], 0, 0, 0);
                        acc[n] = __builtin_amdgcn_mfma_f32_16x16x32_bf16(al, bh, acc[n], 0, 0, 0);
                    }
                }
            }
            #pragma unroll
            for (int rr = 0; rr < 4; ++rr) {
                const int node = m0 + quad * 4 + rr;
                float* hp = h + (size_t)node * 64 + l16;
                #pragma unroll
                for (int n = 0; n < 4; ++n) {
                    float v = fmaxf(acc[n][rr] + br[l16 + 16 * n], 0.f);
                    hp[16 * n] = v;
                    if (r < 2) Ht[(size_t)(l16 + 16 * n) * GN + node] = f2bf(v);
                }
            }
        }
        __threadfence();
        grid.sync();
    }

    // ---- edge: s_i = h@w_i, s_j = h@w_j (one wave per node) --------------
    for (int node = wid; node < GN; node += NWAVE) {
        const float hv = h[(size_t)node * 64 + lane];
        float vi = hv * Wedge[lane];
        float vj = hv * Wedge[64 + lane];
        #pragma unroll
        for (int off = 32; off > 0; off >>= 1) {
            vi += __shfl_xor(vi, off, 64);
            vj += __shfl_xor(vj, off, 64);
        }
        if (lane == 0) { s_i[node] = vi; s_j[node] = vj; }
    }
}

// ---------------- scores: out[i][j] = s_i[i] + s_j[j] + be, diag 0 ------
__global__ __launch_bounds__(256) void scores_k(
    const float* __restrict__ s_i, const float* __restrict__ s_j,
    const float* __restrict__ be, float* __restrict__ out)
{
    const int i  = blockIdx.y;
    const int j0 = (blockIdx.x * 256 + threadIdx.x) * 4;
    const float si = s_i[i] + be[0];
    const float4 sj = *(const float4*)(s_j + j0);
    float4 o = make_float4(si + sj.x, si + sj.y, si + sj.z, si + sj.w);
    const int d = i - j0;
    if (d >= 0 && d < 4) (&o.x)[d] = 0.f;
    *(float4*)(out + (size_t)i * GN + j0) = o;
}

extern "C" void kernel_launch(void* const* d_in, const int* in_sizes, int n_in,
                              void* d_out, int out_size, void* d_ws, size_t ws_size,
                              hipStream_t stream) {
    const float* X     = (const float*)d_in[0];
    const float* A     = (const float*)d_in[1];
    const float* Wenc  = (const float*)d_in[2];
    const float* benc  = (const float*)d_in[3];
    const float* W1    = (const float*)d_in[4];
    const float* b1    = (const float*)d_in[5];
    const float* W2    = (const float*)d_in[6];
    const float* b2    = (const float*)d_in[7];
    const float* W3    = (const float*)d_in[8];
    const float* b3    = (const float*)d_in[9];
    const float* Wedge = (const float*)d_in[10];
    const float* bedge = (const float*)d_in[11];
    float* out = (float*)d_out;

    char* ws = (char*)d_ws;
    float* part = (float*)ws;                                   // 4 MiB
    short* Abf  = (short*)(ws + ((size_t)4 << 20));             // 32 MiB
    float* h    = (float*)(ws + ((size_t)36 << 20));            // 1 MiB
    short* Ht   = (short*)(ws + ((size_t)37 << 20));            // 0.5 MiB
    float* s_i  = (float*)(ws + ((size_t)38 << 20));
    float* s_j  = s_i + GN;

    void* args[] = {
        (void*)&X, (void*)&A, (void*)&Wenc, (void*)&benc,
        (void*)&W1, (void*)&b1, (void*)&W2, (void*)&b2,
        (void*)&W3, (void*)&b3, (void*)&Wedge,
        (void*)&part, (void*)&Abf, (void*)&h,
        (void*)&Ht, (void*)&s_i, (void*)&s_j };
    hipLaunchCooperativeKernel((void*)fused_k, dim3(NBLK), dim3(256),
                               args, 0, stream);

    scores_k<<<dim3(GN / 1024, GN), 256, 0, stream>>>(s_i, s_j, bedge, out);
}